// Round 1
// baseline (21539.107 us; speedup 1.0000x reference)
//
#include <hip/hip_runtime.h>
#include <math.h>

// ---------------------------------------------------------------------------
// VQ-VAE forward, fp32. Shapes:
//  x (1024,1,50,50) -> conv1 k3 s2 p1 relu -> h1 (1024,32,25,25)
//  -> conv2 k3 s2 p1 relu -> h2 (1024,64,13,13)
//  -> conv3 1x1 (fused into VQ kernel) -> z (64-dim per pixel)
//  -> VQ vs codebook (512,64): q = codebook[argmin dist], loss = 1.25*mean((q-z)^2)
//  -> tconv1 k3 s2 p1 op0 relu: 13->25, 64ch
//  -> tconv2 k3 s2 p1 op1 relu: 25->50, 32ch
//  -> conv k3 s1 p1 + sigmoid -> x_recon (1024,1,50,50)
// d_out = x_recon (2,560,000 f32) then vq_loss (1 f32).
// ---------------------------------------------------------------------------

__global__ __launch_bounds__(64) void k_zero(float* __restrict__ p) {
    if (threadIdx.x == 0 && blockIdx.x == 0) *p = 0.f;
}

// conv1: (bc,1,50,50) -> (bc,32,25,25), k3 s2 p1, relu
__global__ __launch_bounds__(256) void k_conv1(const float* __restrict__ x,
                                               const float* __restrict__ w,
                                               const float* __restrict__ b,
                                               float* __restrict__ out, int total) {
    int i = blockIdx.x * 256 + threadIdx.x;
    if (i >= total) return;
    int ow = i % 25, oh = (i / 25) % 25, co = (i / 625) % 32, n = i / 20000;
    const float* xp = x + (size_t)n * 2500;
    const float* wp = w + co * 9;
    float s = b[co];
#pragma unroll
    for (int kh = 0; kh < 3; ++kh) {
        int ih = 2 * oh - 1 + kh;
        if ((unsigned)ih >= 50u) continue;
#pragma unroll
        for (int kw = 0; kw < 3; ++kw) {
            int iw = 2 * ow - 1 + kw;
            if ((unsigned)iw >= 50u) continue;
            s += xp[ih * 50 + iw] * wp[kh * 3 + kw];
        }
    }
    out[i] = fmaxf(s, 0.f);
}

// conv2: (bc,32,25,25) -> (bc,64,13,13), k3 s2 p1, relu
__global__ __launch_bounds__(256) void k_conv2(const float* __restrict__ in,
                                               const float* __restrict__ w,
                                               const float* __restrict__ b,
                                               float* __restrict__ out, int total) {
    int i = blockIdx.x * 256 + threadIdx.x;
    if (i >= total) return;
    int ow = i % 13, oh = (i / 13) % 13, co = (i / 169) % 64, n = i / 10816;
    const float* ip = in + (size_t)n * 20000;
    const float* wp = w + co * 288;  // 32*9
    float s = b[co];
#pragma unroll
    for (int kh = 0; kh < 3; ++kh) {
        int ih = 2 * oh - 1 + kh;
        if ((unsigned)ih >= 25u) continue;
#pragma unroll
        for (int kw = 0; kw < 3; ++kw) {
            int iw = 2 * ow - 1 + kw;
            if ((unsigned)iw >= 25u) continue;
            const float* ii = ip + ih * 25 + iw;
            const float* ww = wp + kh * 3 + kw;
#pragma unroll
            for (int ci = 0; ci < 32; ++ci)
                s += ii[ci * 625] * ww[ci * 9];
        }
    }
    out[i] = fmaxf(s, 0.f);
}

// fused conv3(1x1) + VQ: h2 (bc,64,13,13) -> q (bc,64,13,13); loss atomicAdd
__global__ __launch_bounds__(256) void k_vq(const float* __restrict__ h2,
                                            const float* __restrict__ w3,
                                            const float* __restrict__ b3,
                                            const float* __restrict__ cb,
                                            float* __restrict__ q,
                                            float* __restrict__ loss, int npix) {
    __shared__ float w3s[64 * 64];
    __shared__ float cn[512];
    __shared__ float red[4];
    int tid = threadIdx.x;
    for (int j = tid; j < 4096; j += 256) w3s[j] = w3[j];
    for (int k = tid; k < 512; k += 256) {
        float s = 0.f;
        const float* cr = cb + k * 64;
#pragma unroll
        for (int c = 0; c < 64; ++c) s += cr[c] * cr[c];
        cn[k] = s;
    }
    __syncthreads();

    int i = blockIdx.x * 256 + tid;
    float lsum = 0.f;
    if (i < npix) {
        int p = i % 169, n = i / 169;
        const float* hp = h2 + (size_t)n * 10816 + p;  // stride 169 between channels
        float z[64];
#pragma unroll
        for (int c = 0; c < 64; ++c) z[c] = b3[c];
        for (int ci = 0; ci < 64; ++ci) {
            float v = hp[ci * 169];
            const float* wr = w3s + ci;  // w3s[c*64 + ci]
#pragma unroll
            for (int c = 0; c < 64; ++c) z[c] += wr[c * 64] * v;
        }
        float best = 3.4e38f;
        int bk = 0;
        for (int k = 0; k < 512; ++k) {
            const float* cr = cb + k * 64;  // uniform across wave -> scalar loads
            float dot = 0.f;
#pragma unroll
            for (int c = 0; c < 64; ++c) dot += z[c] * cr[c];
            float d = cn[k] - 2.f * dot;
            if (d < best) { best = d; bk = k; }
        }
        const float* cq = cb + bk * 64;
        float* qp = q + (size_t)n * 10816 + p;
#pragma unroll
        for (int c = 0; c < 64; ++c) {
            float qv = cq[c];
            float dd = qv - z[c];
            lsum += dd * dd;
            qp[c * 169] = qv;
        }
    }
    // block reduction: 4 waves of 64
#pragma unroll
    for (int off = 32; off > 0; off >>= 1) lsum += __shfl_down(lsum, off);
    if ((tid & 63) == 0) red[tid >> 6] = lsum;
    __syncthreads();
    if (tid == 0) {
        float t = red[0] + red[1] + red[2] + red[3];
        // loss = 1.25 * sum / (1024*64*13*13)
        atomicAdd(loss, t * (1.25f / 11075584.f));
    }
}

// tconv1: q (bc,64,13,13) -> (bc,64,25,25), k3 s2 p1 op0, relu
__global__ __launch_bounds__(256) void k_tconv1(const float* __restrict__ in,
                                                const float* __restrict__ w,
                                                const float* __restrict__ b,
                                                float* __restrict__ out, int total) {
    int i = blockIdx.x * 256 + threadIdx.x;
    if (i >= total) return;
    int ow = i % 25, oh = (i / 25) % 25, co = (i / 625) % 64, n = i / 40000;
    const float* ip = in + (size_t)n * 10816;
    const float* wp = w + co * 576;  // 64*9
    float s = b[co];
#pragma unroll
    for (int jh = 0; jh < 3; ++jh) {
        int th = oh + 1 - jh;
        if (th & 1) continue;
        int ih = th >> 1;
        if ((unsigned)ih >= 13u) continue;
#pragma unroll
        for (int jw = 0; jw < 3; ++jw) {
            int tw = ow + 1 - jw;
            if (tw & 1) continue;
            int iw = tw >> 1;
            if ((unsigned)iw >= 13u) continue;
            const float* ii = ip + ih * 13 + iw;
            const float* ww = wp + jh * 3 + jw;
#pragma unroll
            for (int ci = 0; ci < 64; ++ci)
                s += ii[ci * 169] * ww[ci * 9];
        }
    }
    out[i] = fmaxf(s, 0.f);
}

// tconv2: (bc,64,25,25) -> (bc,32,50,50), k3 s2 p1 op1, relu
__global__ __launch_bounds__(256) void k_tconv2(const float* __restrict__ in,
                                                const float* __restrict__ w,
                                                const float* __restrict__ b,
                                                float* __restrict__ out, int total) {
    int i = blockIdx.x * 256 + threadIdx.x;
    if (i >= total) return;
    int ow = i % 50, oh = (i / 50) % 50, co = (i / 2500) % 32, n = i / 80000;
    const float* ip = in + (size_t)n * 40000;
    const float* wp = w + co * 576;  // 64*9
    float s = b[co];
#pragma unroll
    for (int jh = 0; jh < 3; ++jh) {
        int th = oh + 1 - jh;
        if (th & 1) continue;
        int ih = th >> 1;
        if ((unsigned)ih >= 25u) continue;
#pragma unroll
        for (int jw = 0; jw < 3; ++jw) {
            int tw = ow + 1 - jw;
            if (tw & 1) continue;
            int iw = tw >> 1;
            if ((unsigned)iw >= 25u) continue;
            const float* ii = ip + ih * 25 + iw;
            const float* ww = wp + jh * 3 + jw;
#pragma unroll
            for (int ci = 0; ci < 64; ++ci)
                s += ii[ci * 625] * ww[ci * 9];
        }
    }
    out[i] = fmaxf(s, 0.f);
}

// final conv: (bc,32,50,50) -> (bc,1,50,50), k3 s1 p1, sigmoid
__global__ __launch_bounds__(256) void k_convf(const float* __restrict__ in,
                                               const float* __restrict__ w,
                                               const float* __restrict__ b,
                                               float* __restrict__ out, int total) {
    int i = blockIdx.x * 256 + threadIdx.x;
    if (i >= total) return;
    int ow = i % 50, oh = (i / 50) % 50, n = i / 2500;
    const float* ip = in + (size_t)n * 80000;
    float s = b[0];
#pragma unroll
    for (int kh = 0; kh < 3; ++kh) {
        int ih = oh - 1 + kh;
        if ((unsigned)ih >= 50u) continue;
#pragma unroll
        for (int kw = 0; kw < 3; ++kw) {
            int iw = ow - 1 + kw;
            if ((unsigned)iw >= 50u) continue;
            const float* ii = ip + ih * 50 + iw;
            const float* ww = w + kh * 3 + kw;
#pragma unroll
            for (int ci = 0; ci < 32; ++ci)
                s += ii[ci * 2500] * ww[ci * 9];
        }
    }
    out[i] = 1.f / (1.f + expf(-s));
}

extern "C" void kernel_launch(void* const* d_in, const int* in_sizes, int n_in,
                              void* d_out, int out_size, void* d_ws, size_t ws_size,
                              hipStream_t stream) {
    const float* x   = (const float*)d_in[0];
    const float* ew1 = (const float*)d_in[1];
    const float* eb1 = (const float*)d_in[2];
    const float* ew2 = (const float*)d_in[3];
    const float* eb2 = (const float*)d_in[4];
    const float* ew3 = (const float*)d_in[5];
    const float* eb3 = (const float*)d_in[6];
    const float* cb  = (const float*)d_in[7];
    const float* dw1 = (const float*)d_in[8];
    const float* db1 = (const float*)d_in[9];
    const float* dw2 = (const float*)d_in[10];
    const float* db2 = (const float*)d_in[11];
    const float* dw3 = (const float*)d_in[12];
    const float* db3 = (const float*)d_in[13];
    float* out = (float*)d_out;
    float* loss = out + 2560000;

    const int B = 1024;
    // Aliased regions per image (floats): A = max(h1=20000, q=10816, d2=80000)
    //                                     Bp = max(h2=10816, d1=40000)
    const size_t A_per = 80000, B_per = 40000;
    const size_t bytes_per_img = (A_per + B_per) * sizeof(float);  // 480000
    int BC = (int)(ws_size / bytes_per_img);
    if (BC > B) BC = B;
    if (BC < 1) BC = 1;
    float* regA = (float*)d_ws;
    float* regB = regA + (size_t)BC * A_per;

    k_zero<<<1, 64, 0, stream>>>(loss);

    for (int n0 = 0; n0 < B; n0 += BC) {
        int bc = (B - n0 < BC) ? (B - n0) : BC;
        const float* xch = x + (size_t)n0 * 2500;

        int t1 = bc * 20000;  // h1
        k_conv1<<<(t1 + 255) / 256, 256, 0, stream>>>(xch, ew1, eb1, regA, t1);

        int t2 = bc * 10816;  // h2
        k_conv2<<<(t2 + 255) / 256, 256, 0, stream>>>(regA, ew2, eb2, regB, t2);

        int npix = bc * 169;  // fused conv3 + VQ: regB (h2) -> regA (q)
        k_vq<<<(npix + 255) / 256, 256, 0, stream>>>(regB, ew3, eb3, cb, regA, loss, npix);

        int t4 = bc * 40000;  // d1
        k_tconv1<<<(t4 + 255) / 256, 256, 0, stream>>>(regA, dw1, db1, regB, t4);

        int t5 = bc * 80000;  // d2
        k_tconv2<<<(t5 + 255) / 256, 256, 0, stream>>>(regB, dw2, db2, regA, t5);

        int t6 = bc * 2500;  // x_recon chunk
        k_convf<<<(t6 + 255) / 256, 256, 0, stream>>>(regA, dw3, db3, out + (size_t)n0 * 2500, t6);
    }
}